// Round 9
// baseline (136.216 us; speedup 1.0000x reference)
//
#include <hip/hip_runtime.h>
#include <hip/hip_bf16.h>

#define EMB_DIM 128

// Kernel 1: start[n] = lower_bound(segment_ids, n) for n in [0, N]
__global__ void seg_starts_kernel(const int* __restrict__ seg, int E, int N,
                                  int* __restrict__ start) {
    int n = blockIdx.x * blockDim.x + threadIdx.x;
    if (n > N) return;
    int lo = 0, hi = E;
    while (lo < hi) {
        int mid = (lo + hi) >> 1;
        if (seg[mid] < n) lo = mid + 1; else hi = mid;
    }
    start[n] = lo;
}

// Kernel 2: one 256-thread block per node.
//   group g = t/32 (8 edge-groups), lane c = t%32 (column quad: cols 4c..4c+3)
__global__ void seg_mean_kernel(const float* __restrict__ W,
                                const int* __restrict__ idx,
                                const int* __restrict__ start,
                                float* __restrict__ out) {
    int n = blockIdx.x;
    int t = threadIdx.x;          // 0..255
    int g = t >> 5;               // 0..7
    int c = t & 31;               // 0..31
    int s = start[n];
    int e = start[n + 1];

    float4 acc = make_float4(0.f, 0.f, 0.f, 0.f);
    for (int j = s + g; j < e; j += 8) {
        int r = idx[j];
        const float4* row = (const float4*)(W + (long long)r * EMB_DIM);
        float4 v = row[c];
        acc.x += v.x; acc.y += v.y; acc.z += v.z; acc.w += v.w;
    }

    __shared__ float4 red[8][32];
    red[g][c] = acc;
    __syncthreads();

    if (g == 0) {
        float4 a = red[0][c];
        #pragma unroll
        for (int gg = 1; gg < 8; ++gg) {
            float4 v = red[gg][c];
            a.x += v.x; a.y += v.y; a.z += v.z; a.w += v.w;
        }
        float inv = 1.0f / fmaxf((float)(e - s), 1.0f);
        float4 o = make_float4(a.x * inv, a.y * inv, a.z * inv, a.w * inv);
        ((float4*)(out + (long long)n * EMB_DIM))[c] = o;
    }
}

extern "C" void kernel_launch(void* const* d_in, const int* in_sizes, int n_in,
                              void* d_out, int out_size, void* d_ws, size_t ws_size,
                              hipStream_t stream) {
    const float* weight      = (const float*)d_in[0];
    const int*   neigh_idx   = (const int*)d_in[1];
    const int*   segment_ids = (const int*)d_in[2];
    int N = out_size / EMB_DIM;       // 10000
    int E = in_sizes[1];              // 320000

    int* start = (int*)d_ws;          // (N+1) ints

    {
        int threads = 256;
        int blocks = (N + 1 + threads - 1) / threads;
        seg_starts_kernel<<<blocks, threads, 0, stream>>>(segment_ids, E, N, start);
    }
    // DIAGNOSTIC: launch seg_mean twice. It is idempotent (writes only, same
    // values), so correctness is unchanged; dur_us_new - dur_us_old isolates
    // one seg_mean execution time, which the top-5 profile view hides.
    seg_mean_kernel<<<N, 256, 0, stream>>>(weight, neigh_idx, start, (float*)d_out);
    seg_mean_kernel<<<N, 256, 0, stream>>>(weight, neigh_idx, start, (float*)d_out);
}

// Round 10
// 128.151 us; speedup vs baseline: 1.0629x; 1.0629x over previous
//
#include <hip/hip_runtime.h>
#include <hip/hip_bf16.h>

#define EMB_DIM 128

// One 256-thread block per node. Threads 0/1 binary-search the sorted
// segment_ids for this node's edge range [s,e); then
//   group g = t/32 (8 edge-groups), lane c = t%32 (one float4 = cols 4c..4c+3)
// accumulates rows j = s+g, s+g+8, ... (32 lanes x 16B = full 512B row per
// half-wave), LDS-reduce across groups, group 0 scales by 1/count and writes.
__global__ void seg_mean_fused_kernel(const float* __restrict__ W,
                                      const int* __restrict__ idx,
                                      const int* __restrict__ seg,
                                      int E,
                                      float* __restrict__ out) {
    int n = blockIdx.x;
    int t = threadIdx.x;          // 0..255

    __shared__ int bounds[2];     // bounds[0]=start[n], bounds[1]=start[n+1]
    if (t < 2) {
        int target = n + t;       // lower_bound(seg, target)
        int lo = 0, hi = E;
        while (lo < hi) {
            int mid = (lo + hi) >> 1;
            if (seg[mid] < target) lo = mid + 1; else hi = mid;
        }
        bounds[t] = lo;
    }
    __syncthreads();
    int s = bounds[0];
    int e = bounds[1];

    int g = t >> 5;               // 0..7
    int c = t & 31;               // 0..31

    float4 acc = make_float4(0.f, 0.f, 0.f, 0.f);
    for (int j = s + g; j < e; j += 8) {
        int r = idx[j];
        const float4* row = (const float4*)(W + (long long)r * EMB_DIM);
        float4 v = row[c];
        acc.x += v.x; acc.y += v.y; acc.z += v.z; acc.w += v.w;
    }

    __shared__ float4 red[8][32];
    red[g][c] = acc;
    __syncthreads();

    if (g == 0) {
        float4 a = red[0][c];
        #pragma unroll
        for (int gg = 1; gg < 8; ++gg) {
            float4 v = red[gg][c];
            a.x += v.x; a.y += v.y; a.z += v.z; a.w += v.w;
        }
        float inv = 1.0f / fmaxf((float)(e - s), 1.0f);
        float4 o = make_float4(a.x * inv, a.y * inv, a.z * inv, a.w * inv);
        ((float4*)(out + (long long)n * EMB_DIM))[c] = o;
    }
}

extern "C" void kernel_launch(void* const* d_in, const int* in_sizes, int n_in,
                              void* d_out, int out_size, void* d_ws, size_t ws_size,
                              hipStream_t stream) {
    const float* weight      = (const float*)d_in[0];
    const int*   neigh_idx   = (const int*)d_in[1];
    const int*   segment_ids = (const int*)d_in[2];
    int N = out_size / EMB_DIM;       // 10000
    int E = in_sizes[1];              // 320000

    seg_mean_fused_kernel<<<N, 256, 0, stream>>>(weight, neigh_idx, segment_ids,
                                                 E, (float*)d_out);
}

// Round 11
// 108.848 us; speedup vs baseline: 1.2514x; 1.1773x over previous
//
#include <hip/hip_runtime.h>
#include <hip/hip_bf16.h>

#define EMB_DIM 128
#define LIDX_CAP 2048   // LDS idx staging capacity (segments avg 32, max ~60)

// Kernel 1: start[n] = lower_bound(segment_ids, n) for n in [0, N]
// 10001 independent binary searches, all latency-overlapped.
__global__ void seg_starts_kernel(const int* __restrict__ seg, int E, int N,
                                  int* __restrict__ start) {
    int n = blockIdx.x * blockDim.x + threadIdx.x;
    if (n > N) return;
    int lo = 0, hi = E;
    while (lo < hi) {
        int mid = (lo + hi) >> 1;
        if (seg[mid] < n) lo = mid + 1; else hi = mid;
    }
    start[n] = lo;
}

// Kernel 2: one 256-thread block per node.
//   Stage idx[s..e) into LDS (coalesced), then group g = t/32 accumulates
//   rows j = g, g+8, g+16, ... with a 4-deep unroll (4 independent float4
//   row-loads in flight per thread), LDS-reduce across groups, write.
__global__ void seg_mean_kernel(const float* __restrict__ W,
                                const int* __restrict__ idx,
                                const int* __restrict__ start,
                                float* __restrict__ out) {
    int n = blockIdx.x;
    int t = threadIdx.x;          // 0..255
    int g = t >> 5;               // 0..7
    int c = t & 31;               // 0..31
    int s = start[n];
    int e = start[n + 1];
    int cnt = e - s;

    __shared__ int lidx[LIDX_CAP];
    for (int j = t; j < cnt && j < LIDX_CAP; j += 256)
        lidx[j] = idx[s + j];
    __syncthreads();

    const float4* Wv = (const float4*)W;   // row r starts at Wv[r*32]

    float4 a0 = make_float4(0.f,0.f,0.f,0.f);
    float4 a1 = make_float4(0.f,0.f,0.f,0.f);
    float4 a2 = make_float4(0.f,0.f,0.f,0.f);
    float4 a3 = make_float4(0.f,0.f,0.f,0.f);

    int j = g;
    // main: 4 independent row loads per iteration (rows j, j+8, j+16, j+24)
    for (; j + 24 < cnt; j += 32) {
        int r0 = lidx[j];
        int r1 = lidx[j + 8];
        int r2 = lidx[j + 16];
        int r3 = lidx[j + 24];
        float4 v0 = Wv[r0 * 32 + c];
        float4 v1 = Wv[r1 * 32 + c];
        float4 v2 = Wv[r2 * 32 + c];
        float4 v3 = Wv[r3 * 32 + c];
        a0.x += v0.x; a0.y += v0.y; a0.z += v0.z; a0.w += v0.w;
        a1.x += v1.x; a1.y += v1.y; a1.z += v1.z; a1.w += v1.w;
        a2.x += v2.x; a2.y += v2.y; a2.z += v2.z; a2.w += v2.w;
        a3.x += v3.x; a3.y += v3.y; a3.z += v3.z; a3.w += v3.w;
    }
    // tail
    for (; j < cnt; j += 8) {
        int r = (j < LIDX_CAP) ? lidx[j] : idx[s + j];
        float4 v = Wv[r * 32 + c];
        a0.x += v.x; a0.y += v.y; a0.z += v.z; a0.w += v.w;
    }

    a0.x += a1.x + a2.x + a3.x;
    a0.y += a1.y + a2.y + a3.y;
    a0.z += a1.z + a2.z + a3.z;
    a0.w += a1.w + a2.w + a3.w;

    __shared__ float4 red[8][32];
    red[g][c] = a0;
    __syncthreads();

    if (g == 0) {
        float4 a = red[0][c];
        #pragma unroll
        for (int gg = 1; gg < 8; ++gg) {
            float4 v = red[gg][c];
            a.x += v.x; a.y += v.y; a.z += v.z; a.w += v.w;
        }
        float inv = 1.0f / fmaxf((float)cnt, 1.0f);
        float4 o = make_float4(a.x * inv, a.y * inv, a.z * inv, a.w * inv);
        ((float4*)(out + (long long)n * EMB_DIM))[c] = o;
    }
}

extern "C" void kernel_launch(void* const* d_in, const int* in_sizes, int n_in,
                              void* d_out, int out_size, void* d_ws, size_t ws_size,
                              hipStream_t stream) {
    const float* weight      = (const float*)d_in[0];
    const int*   neigh_idx   = (const int*)d_in[1];
    const int*   segment_ids = (const int*)d_in[2];
    int N = out_size / EMB_DIM;       // 10000
    int E = in_sizes[1];              // 320000

    int* start = (int*)d_ws;          // (N+1) ints

    {
        int threads = 256;
        int blocks = (N + 1 + threads - 1) / threads;
        seg_starts_kernel<<<blocks, threads, 0, stream>>>(segment_ids, E, N, start);
    }
    seg_mean_kernel<<<N, 256, 0, stream>>>(weight, neigh_idx, start, (float*)d_out);
}